// Round 2
// 187.672 us; speedup vs baseline: 1.0317x; 1.0317x over previous
//
#include <hip/hip_runtime.h>
#include <math.h>

// Problem constants (from reference setup_inputs)
#define BATCH   128
#define NCLS    200
#define KATTR   312
#define MH      28
#define MW      28
#define NMAPS   (BATCH * KATTR)        // 39936
#define MAP_ELEMS (MH * MW)            // 784
#define MAP_GROUPS (MAP_ELEMS / 4)     // 196 float4 per map
#define NREG    (BATCH * KATTR)        // 39936 elements in MSE

// Work partition: cheap CLS/REG blocks FIRST so they overlap CPT ramp-up.
#define MAPS_PER_WAVE   8
#define WAVES_PER_BLOCK 4
#define MAPS_PER_BLOCK  (MAPS_PER_WAVE * WAVES_PER_BLOCK)   // 32
#define CPT_BLOCKS      (NMAPS / MAPS_PER_BLOCK)            // 1248 (exact)
#define CLS_BLOCKS      (BATCH / WAVES_PER_BLOCK)           // 32
#define REG_BLOCKS      8
#define HEAD_BLOCKS     (CLS_BLOCKS + REG_BLOCKS)           // 40
#define TOTAL_BLOCKS    (CPT_BLOCKS + HEAD_BLOCKS)

// ws layout (floats)
#define WS_CLS  0                       // 128 per-row CE values
#define WS_REG  (WS_CLS + BATCH)        // 8 MSE partials
#define WS_CPT  (WS_REG + REG_BLOCKS)   // 1248 cpt partials
#define WS_TOTAL (WS_CPT + CPT_BLOCKS)  // 1384 floats ~ 5.5 KB

#define COEF_CLS 1.0f
#define COEF_REG 1.0f
#define COEF_CPT 0.01f

// compile-time float4 element select (keeps vectors in registers)
#define ELEM(v4, j) ((j) == 0 ? (v4).x : (j) == 1 ? (v4).y : (j) == 2 ? (v4).z : (v4).w)

// native clang vector type — __builtin_nontemporal_load rejects HIP_vector_type
typedef float v4f __attribute__((ext_vector_type(4)));

__device__ __forceinline__ float4 ldnt(const float4* p) {
    const v4f r = __builtin_nontemporal_load((const v4f*)p);
    return make_float4(r.x, r.y, r.z, r.w);
}

__global__ __launch_bounds__(256) void apn_main(
    const float* __restrict__ class_scores,   // [128,200]
    const float* __restrict__ pred,           // [128,312]
    const float* __restrict__ gt,             // [128,312]
    const float* __restrict__ attn,           // [128,312,28,28]
    const int*   __restrict__ class_ids,      // [128]
    float* __restrict__ ws)
{
    const int tid  = threadIdx.x;
    const int lane = tid & 63;
    const int wave = tid >> 6;
    const int blk  = blockIdx.x;

    __shared__ float lds[WAVES_PER_BLOCK];

    if (blk >= HEAD_BLOCKS) {
        // ---- concentration loss: 1 wave per map, 8 maps per wave,
        //      register double-buffered across maps ----
        const int cb = blk - HEAD_BLOCKS;
        const int m0 = cb * MAPS_PER_BLOCK + wave * MAPS_PER_WAVE;
        const float4* __restrict__ base =
            (const float4*)(attn + (size_t)m0 * MAP_ELEMS);

        // Per-lane h/w coordinates for the 16 elements this lane covers.
        // Depends only on lane -> computed once per block, kept in VGPRs.
        float hfv[4][4], wfv[4][4];
        #pragma unroll
        for (int t = 0; t < 4; ++t) {
            #pragma unroll
            for (int j = 0; j < 4; ++j) {
                const int idx = (lane + 64 * t) * 4 + j;
                const int h = idx / MW;
                hfv[t][j] = (float)h;
                wfv[t][j] = (float)(idx - h * MW);
            }
        }

        const bool tail = (lane < (MAP_GROUPS - 192));   // lanes 0..3 own group 192+lane
        const float4 z4 = make_float4(0.f, 0.f, 0.f, 0.f);
        const int lane4 = lane << 2;

        float4 cur[4], nxt[4];

        // prologue: load map 0
        #pragma unroll
        for (int t = 0; t < 3; ++t) cur[t] = ldnt(base + lane + 64 * t);
        if (tail) cur[3] = ldnt(base + lane + 192); else cur[3] = z4;

        float wsum = 0.0f;   // per-lane accumulator across all 8 maps

        #pragma unroll
        for (int mm = 0; mm < MAPS_PER_WAVE; ++mm) {
            // issue next map's loads before touching this map's data
            if (mm + 1 < MAPS_PER_WAVE) {
                const float4* __restrict__ bp = base + (size_t)(mm + 1) * MAP_GROUPS;
                #pragma unroll
                for (int t = 0; t < 3; ++t) nxt[t] = ldnt(bp + lane + 64 * t);
                if (tail) nxt[3] = ldnt(bp + lane + 192); else nxt[3] = z4;
            }

            // pass 1: in-lane argmax scan, ascending flat index
            // (pad zeros at t=3 can never win the strict '>')
            float maxv = -INFINITY;
            int   maxi = 0;
            #pragma unroll
            for (int t = 0; t < 4; ++t) {
                #pragma unroll
                for (int j = 0; j < 4; ++j) {
                    const float v = ELEM(cur[t], j);
                    const int idx = lane4 + t * 256 + j;
                    if (v > maxv) { maxv = v; maxi = idx; }
                }
            }

            // wave argmax reduce (min flat index on ties == jnp.argmax semantics)
            #pragma unroll
            for (int off = 1; off < 64; off <<= 1) {
                const float ov = __shfl_xor(maxv, off);
                const int   oi = __shfl_xor(maxi, off);
                if (ov > maxv || (ov == maxv && oi < maxi)) { maxv = ov; maxi = oi; }
            }

            const float chf = (float)(maxi / MW);
            const float cwf = (float)(maxi % MW);

            // pass 2: distance-weighted partial sum (register-resident data,
            // precomputed coordinates -> 5 VALU ops/element)
            #pragma unroll
            for (int t = 0; t < 4; ++t) {
                #pragma unroll
                for (int j = 0; j < 4; ++j) {
                    const float dh = hfv[t][j] - chf;
                    const float dw = wfv[t][j] - cwf;
                    wsum += ELEM(cur[t], j) * (dh * dh + dw * dw);
                }
            }

            if (mm + 1 < MAPS_PER_WAVE) {
                #pragma unroll
                for (int t = 0; t < 4; ++t) cur[t] = nxt[t];   // register rename after unroll
            }
        }

        // wave sum reduce
        #pragma unroll
        for (int off = 1; off < 64; off <<= 1) wsum += __shfl_xor(wsum, off);
        if (lane == 0) lds[wave] = wsum;
        __syncthreads();
        if (tid == 0) ws[WS_CPT + cb] = lds[0] + lds[1] + lds[2] + lds[3];

    } else if (blk < CLS_BLOCKS) {
        // ---- cross-entropy: 1 wave per batch row ----
        const int row = blk * WAVES_PER_BLOCK + wave;
        const float* __restrict__ xr = class_scores + (size_t)row * NCLS;

        float xv[4];
        float m = -INFINITY;
        #pragma unroll
        for (int t = 0; t < 4; ++t) {
            const int c = lane + 64 * t;
            if (c < NCLS) { xv[t] = xr[c]; m = fmaxf(m, xv[t]); }
            else            xv[t] = -INFINITY;
        }
        #pragma unroll
        for (int off = 1; off < 64; off <<= 1) m = fmaxf(m, __shfl_xor(m, off));

        float se = 0.0f;
        #pragma unroll
        for (int t = 0; t < 4; ++t) {
            const int c = lane + 64 * t;
            if (c < NCLS) se += expf(xv[t] - m);
        }
        #pragma unroll
        for (int off = 1; off < 64; off <<= 1) se += __shfl_xor(se, off);

        if (lane == 0) {
            const int cid = class_ids[row];
            const float lse = m + logf(se);
            ws[WS_CLS + row] = lse - xr[cid];
        }

    } else {
        // ---- MSE: float4 grid-stride over 9984 float4 groups ----
        const int rb = blk - CLS_BLOCKS;   // 0..7
        const float4* __restrict__ p = (const float4*)pred;
        const float4* __restrict__ q = (const float4*)gt;
        float s = 0.0f;
        for (int i = rb * 256 + tid; i < NREG / 4; i += REG_BLOCKS * 256) {
            const float4 a = p[i];
            const float4 b = q[i];
            const float dx = a.x - b.x, dy = a.y - b.y, dz = a.z - b.z, dw = a.w - b.w;
            s += dx * dx + dy * dy + dz * dz + dw * dw;
        }
        #pragma unroll
        for (int off = 1; off < 64; off <<= 1) s += __shfl_xor(s, off);
        if (lane == 0) lds[wave] = s;
        __syncthreads();
        if (tid == 0) ws[WS_REG + rb] = lds[0] + lds[1] + lds[2] + lds[3];
    }
}

__global__ __launch_bounds__(256) void apn_final(
    const float* __restrict__ ws, float* __restrict__ out)
{
    const int tid  = threadIdx.x;
    const int lane = tid & 63;
    const int wave = tid >> 6;

    float a = 0.0f, b = 0.0f, c = 0.0f;
    for (int i = tid; i < BATCH; i += 256)      a += ws[WS_CLS + i];
    if (tid < REG_BLOCKS)                       b  = ws[WS_REG + tid];
    for (int i = tid; i < CPT_BLOCKS; i += 256) c += ws[WS_CPT + i];

    #pragma unroll
    for (int off = 1; off < 64; off <<= 1) {
        a += __shfl_xor(a, off);
        b += __shfl_xor(b, off);
        c += __shfl_xor(c, off);
    }

    __shared__ float la[4], lb[4], lc[4];
    if (lane == 0) { la[wave] = a; lb[wave] = b; lc[wave] = c; }
    __syncthreads();
    if (tid == 0) {
        const float sa = la[0] + la[1] + la[2] + la[3];
        const float sb = lb[0] + lb[1] + lb[2] + lb[3];
        const float sc = lc[0] + lc[1] + lc[2] + lc[3];
        const float l_cls = COEF_CLS * (sa / (float)BATCH);
        const float l_reg = COEF_REG * (sb / (float)NREG);
        const float l_cpt = COEF_CPT * (sc / ((float)NMAPS * (float)MAP_ELEMS));
        out[0] = l_cls;
        out[1] = l_reg;
        out[2] = l_cpt;
        out[3] = l_cls + l_reg + l_cpt;
    }
}

extern "C" void kernel_launch(void* const* d_in, const int* in_sizes, int n_in,
                              void* d_out, int out_size, void* d_ws, size_t ws_size,
                              hipStream_t stream) {
    const float* class_scores = (const float*)d_in[0];
    const float* pred         = (const float*)d_in[1];
    const float* gt           = (const float*)d_in[2];
    const float* attn         = (const float*)d_in[3];
    const int*   class_ids    = (const int*)d_in[4];
    float* ws  = (float*)d_ws;
    float* out = (float*)d_out;

    apn_main<<<dim3(TOTAL_BLOCKS), dim3(256), 0, stream>>>(
        class_scores, pred, gt, attn, class_ids, ws);
    apn_final<<<dim3(1), dim3(256), 0, stream>>>(ws, out);
}

// Round 3
// 182.393 us; speedup vs baseline: 1.0616x; 1.0289x over previous
//
#include <hip/hip_runtime.h>
#include <math.h>

// Problem constants (from reference setup_inputs)
#define BATCH   128
#define NCLS    200
#define KATTR   312
#define MH      28
#define MW      28
#define NMAPS   (BATCH * KATTR)        // 39936
#define MAP_ELEMS (MH * MW)            // 784
#define MAP_GROUPS (MAP_ELEMS / 4)     // 196 float4 per map
#define NREG    (BATCH * KATTR)        // 39936 elements in MSE

// Work partition: cheap CLS/REG blocks FIRST so they overlap CPT ramp-up.
#define MAPS_PER_WAVE   8
#define WAVES_PER_BLOCK 4
#define MAPS_PER_BLOCK  (MAPS_PER_WAVE * WAVES_PER_BLOCK)   // 32
#define CPT_BLOCKS      (NMAPS / MAPS_PER_BLOCK)            // 1248 (exact)
#define CLS_BLOCKS      (BATCH / WAVES_PER_BLOCK)           // 32
#define REG_BLOCKS      8
#define HEAD_BLOCKS     (CLS_BLOCKS + REG_BLOCKS)           // 40
#define TOTAL_BLOCKS    (CPT_BLOCKS + HEAD_BLOCKS)

// ws layout (floats)
#define WS_CLS  0                       // 128 per-row CE values
#define WS_REG  (WS_CLS + BATCH)        // 8 MSE partials
#define WS_CPT  (WS_REG + REG_BLOCKS)   // 1248 cpt partials
#define WS_TOTAL (WS_CPT + CPT_BLOCKS)  // 1384 floats ~ 5.5 KB

#define COEF_CLS 1.0f
#define COEF_REG 1.0f
#define COEF_CPT 0.01f

// compile-time float4 element select (keeps vectors in registers)
#define ELEM(v4, j) ((j) == 0 ? (v4).x : (j) == 1 ? (v4).y : (j) == 2 ? (v4).z : (v4).w)

// native clang vector type — __builtin_nontemporal_load rejects HIP_vector_type
typedef float v4f __attribute__((ext_vector_type(4)));

__device__ __forceinline__ float4 ldnt(const float4* p) {
    const v4f r = __builtin_nontemporal_load((const v4f*)p);
    return make_float4(r.x, r.y, r.z, r.w);
}

__global__ __launch_bounds__(256) void apn_main(
    const float* __restrict__ class_scores,   // [128,200]
    const float* __restrict__ pred,           // [128,312]
    const float* __restrict__ gt,             // [128,312]
    const float* __restrict__ attn,           // [128,312,28,28]
    const int*   __restrict__ class_ids,      // [128]
    float* __restrict__ ws)
{
    const int tid  = threadIdx.x;
    const int lane = tid & 63;
    const int wave = tid >> 6;
    const int blk  = blockIdx.x;

    __shared__ float lds[WAVES_PER_BLOCK];

    if (blk >= HEAD_BLOCKS) {
        // ---- concentration loss: 1 wave per map, 8 maps per wave,
        //      register prefetch depth 2 across maps ----
        const int cb = blk - HEAD_BLOCKS;
        const int m0 = cb * MAPS_PER_BLOCK + wave * MAPS_PER_WAVE;
        const float4* __restrict__ base =
            (const float4*)(attn + (size_t)m0 * MAP_ELEMS);

        // Per-lane h/w coordinates for the 16 elements this lane covers.
        // Depends only on lane -> computed once per block, kept in VGPRs.
        float hfv[4][4], wfv[4][4];
        #pragma unroll
        for (int t = 0; t < 4; ++t) {
            #pragma unroll
            for (int j = 0; j < 4; ++j) {
                const int idx = (lane + 64 * t) * 4 + j;
                const int h = idx / MW;
                hfv[t][j] = (float)h;
                wfv[t][j] = (float)(idx - h * MW);
            }
        }

        const bool tail = (lane < (MAP_GROUPS - 192));   // lanes 0..3 own group 192+lane
        const float4 z4 = make_float4(0.f, 0.f, 0.f, 0.f);
        const int lane4 = lane << 2;

        float4 cur[4], n1[4], n2[4];

        // prologue: maps 0 and 1 in flight
        #pragma unroll
        for (int t = 0; t < 3; ++t) cur[t] = ldnt(base + lane + 64 * t);
        if (tail) cur[3] = ldnt(base + lane + 192); else cur[3] = z4;
        {
            const float4* __restrict__ bp = base + MAP_GROUPS;
            #pragma unroll
            for (int t = 0; t < 3; ++t) n1[t] = ldnt(bp + lane + 64 * t);
            if (tail) n1[3] = ldnt(bp + lane + 192); else n1[3] = z4;
        }

        float wsum = 0.0f;   // per-lane accumulator across all 8 maps

        #pragma unroll
        for (int mm = 0; mm < MAPS_PER_WAVE; ++mm) {
            // keep two maps ahead in flight
            if (mm + 2 < MAPS_PER_WAVE) {
                const float4* __restrict__ bp = base + (size_t)(mm + 2) * MAP_GROUPS;
                #pragma unroll
                for (int t = 0; t < 3; ++t) n2[t] = ldnt(bp + lane + 64 * t);
                if (tail) n2[3] = ldnt(bp + lane + 192); else n2[3] = z4;
            }

            // pass 1: in-lane argmax scan, ascending flat index
            // (pad zeros at t=3 can never win the strict '>')
            float maxv = -INFINITY;
            int   maxi = 0;
            #pragma unroll
            for (int t = 0; t < 4; ++t) {
                #pragma unroll
                for (int j = 0; j < 4; ++j) {
                    const float v = ELEM(cur[t], j);
                    const int idx = lane4 + t * 256 + j;
                    if (v > maxv) { maxv = v; maxi = idx; }
                }
            }

            // wave argmax reduce, packed u64: attn values are uniform [0,1)
            // (non-negative) so IEEE bits are order-monotone; ~idx in the low
            // word gives min-flat-index on ties == jnp.argmax semantics.
            unsigned long long pk =
                ((unsigned long long)__float_as_uint(maxv) << 32) |
                (unsigned int)(~(unsigned int)maxi);
            #pragma unroll
            for (int off = 1; off < 64; off <<= 1) {
                const unsigned long long o = __shfl_xor(pk, off);
                if (o > pk) pk = o;
            }
            const int bmaxi = (int)(~(unsigned int)pk);

            const float chf = (float)(bmaxi / MW);
            const float cwf = (float)(bmaxi % MW);

            // pass 2: distance-weighted partial sum (register-resident data,
            // precomputed coordinates). Arithmetic order identical to prior
            // rounds -> bitwise-stable l_cpt.
            #pragma unroll
            for (int t = 0; t < 4; ++t) {
                #pragma unroll
                for (int j = 0; j < 4; ++j) {
                    const float dh = hfv[t][j] - chf;
                    const float dw = wfv[t][j] - cwf;
                    wsum += ELEM(cur[t], j) * (dh * dh + dw * dw);
                }
            }

            // rotate prefetch buffers (renamed by full unroll)
            if (mm + 1 < MAPS_PER_WAVE) {
                #pragma unroll
                for (int t = 0; t < 4; ++t) cur[t] = n1[t];
            }
            if (mm + 2 < MAPS_PER_WAVE) {
                #pragma unroll
                for (int t = 0; t < 4; ++t) n1[t] = n2[t];
            }
        }

        // wave sum reduce
        #pragma unroll
        for (int off = 1; off < 64; off <<= 1) wsum += __shfl_xor(wsum, off);
        if (lane == 0) lds[wave] = wsum;
        __syncthreads();
        if (tid == 0) ws[WS_CPT + cb] = lds[0] + lds[1] + lds[2] + lds[3];

    } else if (blk < CLS_BLOCKS) {
        // ---- cross-entropy: 1 wave per batch row ----
        const int row = blk * WAVES_PER_BLOCK + wave;
        const float* __restrict__ xr = class_scores + (size_t)row * NCLS;

        float xv[4];
        float m = -INFINITY;
        #pragma unroll
        for (int t = 0; t < 4; ++t) {
            const int c = lane + 64 * t;
            if (c < NCLS) { xv[t] = xr[c]; m = fmaxf(m, xv[t]); }
            else            xv[t] = -INFINITY;
        }
        #pragma unroll
        for (int off = 1; off < 64; off <<= 1) m = fmaxf(m, __shfl_xor(m, off));

        float se = 0.0f;
        #pragma unroll
        for (int t = 0; t < 4; ++t) {
            const int c = lane + 64 * t;
            if (c < NCLS) se += expf(xv[t] - m);
        }
        #pragma unroll
        for (int off = 1; off < 64; off <<= 1) se += __shfl_xor(se, off);

        if (lane == 0) {
            const int cid = class_ids[row];
            const float lse = m + logf(se);
            ws[WS_CLS + row] = lse - xr[cid];
        }

    } else {
        // ---- MSE: float4 grid-stride over 9984 float4 groups ----
        const int rb = blk - CLS_BLOCKS;   // 0..7
        const float4* __restrict__ p = (const float4*)pred;
        const float4* __restrict__ q = (const float4*)gt;
        float s = 0.0f;
        for (int i = rb * 256 + tid; i < NREG / 4; i += REG_BLOCKS * 256) {
            const float4 a = p[i];
            const float4 b = q[i];
            const float dx = a.x - b.x, dy = a.y - b.y, dz = a.z - b.z, dw = a.w - b.w;
            s += dx * dx + dy * dy + dz * dz + dw * dw;
        }
        #pragma unroll
        for (int off = 1; off < 64; off <<= 1) s += __shfl_xor(s, off);
        if (lane == 0) lds[wave] = s;
        __syncthreads();
        if (tid == 0) ws[WS_REG + rb] = lds[0] + lds[1] + lds[2] + lds[3];
    }
}

__global__ __launch_bounds__(256) void apn_final(
    const float* __restrict__ ws, float* __restrict__ out)
{
    const int tid  = threadIdx.x;
    const int lane = tid & 63;
    const int wave = tid >> 6;

    float a = 0.0f, b = 0.0f, c = 0.0f;
    for (int i = tid; i < BATCH; i += 256)      a += ws[WS_CLS + i];
    if (tid < REG_BLOCKS)                       b  = ws[WS_REG + tid];
    for (int i = tid; i < CPT_BLOCKS; i += 256) c += ws[WS_CPT + i];

    #pragma unroll
    for (int off = 1; off < 64; off <<= 1) {
        a += __shfl_xor(a, off);
        b += __shfl_xor(b, off);
        c += __shfl_xor(c, off);
    }

    __shared__ float la[4], lb[4], lc[4];
    if (lane == 0) { la[wave] = a; lb[wave] = b; lc[wave] = c; }
    __syncthreads();
    if (tid == 0) {
        const float sa = la[0] + la[1] + la[2] + la[3];
        const float sb = lb[0] + lb[1] + lb[2] + lb[3];
        const float sc = lc[0] + lc[1] + lc[2] + lc[3];
        const float l_cls = COEF_CLS * (sa / (float)BATCH);
        const float l_reg = COEF_REG * (sb / (float)NREG);
        const float l_cpt = COEF_CPT * (sc / ((float)NMAPS * (float)MAP_ELEMS));
        out[0] = l_cls;
        out[1] = l_reg;
        out[2] = l_cpt;
        out[3] = l_cls + l_reg + l_cpt;
    }
}

extern "C" void kernel_launch(void* const* d_in, const int* in_sizes, int n_in,
                              void* d_out, int out_size, void* d_ws, size_t ws_size,
                              hipStream_t stream) {
    const float* class_scores = (const float*)d_in[0];
    const float* pred         = (const float*)d_in[1];
    const float* gt           = (const float*)d_in[2];
    const float* attn         = (const float*)d_in[3];
    const int*   class_ids    = (const int*)d_in[4];
    float* ws  = (float*)d_ws;
    float* out = (float*)d_out;

    apn_main<<<dim3(TOTAL_BLOCKS), dim3(256), 0, stream>>>(
        class_scores, pred, gt, attn, class_ids, ws);
    apn_final<<<dim3(1), dim3(256), 0, stream>>>(ws, out);
}